// Round 2
// baseline (833.976 us; speedup 1.0000x reference)
//
#include <hip/hip_runtime.h>
#include <math.h>

#define NN 1024
#define BATCH 32
#define NW 16                 // waves per block (1024 threads)
#define RING 512              // boundary ring slots per wave (power of 2)
#define GW 0.05f
#define K2 144.2695040888963f          // (1/gamma) * log2(e): scale into exp2 domain
#define GAMMA_LN2 0.0069314718055994531f  // 1/K2
#define BIGS 1.4426950408889634e11f    // 1e9 * K2 (scaled BIG)

#if __has_builtin(__builtin_amdgcn_exp2f)
#define EXP2F(x) __builtin_amdgcn_exp2f(x)
#else
#define EXP2F(x) exp2f(x)
#endif
#if __has_builtin(__builtin_amdgcn_logf)
#define LOG2F(x) __builtin_amdgcn_logf(x)   // v_log_f32 = log base 2
#else
#define LOG2F(x) log2f(x)
#endif

// One block per batch, 16 waves, NO barriers in the main loop.
// Wave w owns rows [64w, 64w+64). Lane l holds row 64w+l. Per diagonal k:
//   left = own r1 (diag k-1), up = shfl_up(r1) (in-wave) or LDS boundary (lane 0),
//   dg   = previous step's up (register carry).
// Wave w-1 publishes its lane-63 value into a 512-slot LDS ring + release flag;
// wave w spins (rarely: cached monotonic flag) with acquire. One-directional
// lag-1 pipeline => no deadlock. All values kept scaled by K2 so exp2/log2 are
// native and gamma folds into the weight LUT.
__global__ __launch_bounds__(1024) void sdtw_pipe(const float* __restrict__ inp,
                                                  const float* __restrict__ tgt,
                                                  float* __restrict__ partial) {
    __shared__ float xs[NN];
    __shared__ float wl[2 * NN];     // wl[d] = w(|d-1023|) * K2, d = j - i + 1023
    __shared__ float bnd[NW][RING];
    __shared__ int prog[NW];         // producer: last diag published by wave w
    __shared__ int consd[NW];        // consumer: wave w has fully read slots <= consd[w]-2

    const int b = blockIdx.x;
    const int tid = threadIdx.x;
    const int w = tid >> 6;
    const int lane = tid & 63;

    xs[tid] = inp[b * NN + tid];
    const float ti = tgt[b * NN + tid];
    {
        // weight LUT, pre-scaled by K2
        float d0 = fabsf((float)(tid - (NN - 1)));
        wl[tid] = K2 / (1.0f + __expf(-GW * (d0 - (float)NN * 0.5f)));
        float d1 = fabsf((float)(tid + 1));  // |(tid+NN) - (NN-1)|
        wl[tid + NN] = K2 / (1.0f + __expf(-GW * (d1 - (float)NN * 0.5f)));
    }
    if (tid < NW) { prog[tid] = -1; consd[tid] = 0; }
    __syncthreads();  // the only barrier

    float r1 = BIGS;                         // own row, diag k-1 (scaled)
    float dgp = (tid == 0) ? 0.0f : BIGS;    // R(i-1, diag k-2); R(-1,-1)=0 for cell (0,0)
    int progC = -1;                          // cached prog[w-1]
    int consC = 0;                           // cached consd[w+1]

    const float* bndIn = (w > 0) ? bnd[w - 1] : bnd[0];
    float* bndOut = bnd[w];

    int j = -tid;                            // j = k - i
    int xidx = (-tid) & (NN - 1);            // j mod N
    int widx = (NN - 1 - 2 * tid) & (2 * NN - 1);  // (j - i + 1023) mod 2048

    for (int k = 0; k < 2 * NN - 1; ++k) {
        float up = __shfl_up(r1, 1);         // R(i-1, diag k-1), in-wave
        if (w > 0) {
            if (k > 0) {
                if (progC < k - 1) {
                    do {
                        progC = __hip_atomic_load(&prog[w - 1], __ATOMIC_ACQUIRE,
                                                  __HIP_MEMORY_SCOPE_WORKGROUP);
                    } while (progC < k - 1);
                }
                float bv = bndIn[(k - 1) & (RING - 1)];   // broadcast read
                if (lane == 0) up = bv;
            } else {
                if (lane == 0) up = BIGS;
            }
        } else {
            if (lane == 0) up = BIGS;        // row -1
        }
        const float dg = dgp;
        const float left = r1;

        const float x = xs[xidx];
        const float wv = wl[widx];
        const float diff = ti - x;
        const float dk = diff * diff * wv;   // already scaled by K2

        const float mn = fminf(dg, fminf(up, left));
        const float md = __builtin_amdgcn_fmed3f(dg, up, left);
        const float mx = fmaxf(dg, fmaxf(up, left));
        // softmin (scaled): one term is exp2(0)=1 exactly
        const float s = 1.0f + EXP2F(mn - md) + EXP2F(mn - mx);
        float r = dk + mn - LOG2F(s);
        r = ((unsigned)j < (unsigned)NN) ? r : BIGS;

        if (w < NW - 1) {
            // ring back-pressure (cold path; consumer lags ~1 in steady state)
            if ((k & 127) == 0 && k >= RING - 128) {
                if (consC < k - 256) {
                    do {
                        consC = __hip_atomic_load(&consd[w + 1], __ATOMIC_ACQUIRE,
                                                  __HIP_MEMORY_SCOPE_WORKGROUP);
                    } while (consC < k - 256);
                }
            }
            if (lane == 63) {
                bndOut[k & (RING - 1)] = r;
                __hip_atomic_store(&prog[w], k, __ATOMIC_RELEASE,
                                   __HIP_MEMORY_SCOPE_WORKGROUP);
            }
        }
        if (w > 0 && (k & 127) == 0 && lane == 0) {
            __hip_atomic_store(&consd[w], k, __ATOMIC_RELEASE,
                               __HIP_MEMORY_SCOPE_WORKGROUP);
        }

        dgp = up;
        r1 = r;
        ++j;
        xidx = (xidx + 1) & (NN - 1);
        widx = (widx + 1) & (2 * NN - 1);
    }

    if (tid == NN - 1) partial[b] = r1 * GAMMA_LN2;  // unscale
}

__global__ __launch_bounds__(64) void reduce_mean32(const float* __restrict__ partial,
                                                    float* __restrict__ out) {
    float v = (threadIdx.x < BATCH) ? partial[threadIdx.x] : 0.0f;
    #pragma unroll
    for (int off = 32; off > 0; off >>= 1) v += __shfl_down(v, off);
    if (threadIdx.x == 0) out[0] = v * (1.0f / (float)BATCH);
}

extern "C" void kernel_launch(void* const* d_in, const int* in_sizes, int n_in,
                              void* d_out, int out_size, void* d_ws, size_t ws_size,
                              hipStream_t stream) {
    const float* inp = (const float*)d_in[0];  // [B, N, 1]
    const float* tgt = (const float*)d_in[1];  // [B, N, 1]
    float* out = (float*)d_out;                // [1]
    float* partial = (float*)d_ws;             // 32 floats scratch

    sdtw_pipe<<<BATCH, NN, 0, stream>>>(inp, tgt, partial);
    reduce_mean32<<<1, 64, 0, stream>>>(partial, out);
}